// Round 1
// baseline (1683.550 us; speedup 1.0000x reference)
//
#include <hip/hip_runtime.h>
#include <hip/hip_bf16.h>

// Problem constants (derived from in_sizes at launch for safety)
// N=50000, E=800000, IN_F=512, EDGE_F=32, H=4, C=64, H*C=256

#define NEG_SLOPE 0.2f

// ---------------------------------------------------------------------------
// CSR build kernels
// ---------------------------------------------------------------------------
__global__ void hist_kernel(const int* __restrict__ dst, int* __restrict__ cnt, int E) {
    int e = blockIdx.x * 256 + threadIdx.x;
    if (e < E) atomicAdd(&cnt[dst[e]], 1);
}

__global__ void scan_kernel(const int* __restrict__ cnt, int* __restrict__ row_ptr, int N, int E) {
    __shared__ int lds[1024];
    __shared__ int carry_s;
    int t = threadIdx.x;
    if (t == 0) carry_s = 0;
    __syncthreads();
    for (int base = 0; base < N; base += 1024) {
        int v = (base + t < N) ? cnt[base + t] : 0;
        lds[t] = v;
        __syncthreads();
        #pragma unroll
        for (int off = 1; off < 1024; off <<= 1) {
            int add = (t >= off) ? lds[t - off] : 0;
            __syncthreads();
            lds[t] += add;
            __syncthreads();
        }
        int incl = lds[t];
        int carry = carry_s;
        if (base + t < N) row_ptr[base + t] = carry + (incl - v);
        __syncthreads();
        if (t == 1023) carry_s = carry + incl;
        __syncthreads();
    }
    if (t == 0) row_ptr[N] = E;
}

__global__ void copy_int_kernel(const int* __restrict__ a, int* __restrict__ b, int n) {
    int i = blockIdx.x * 256 + threadIdx.x;
    if (i < n) b[i] = a[i];
}

__global__ void scatter_kernel(const int* __restrict__ src, const int* __restrict__ dst,
                               int* __restrict__ cursor, int2* __restrict__ col, int E) {
    int e = blockIdx.x * 256 + threadIdx.x;
    if (e < E) {
        int d = dst[e];
        int pos = atomicAdd(&cursor[d], 1);
        col[pos] = make_int2(src[e], e);
    }
}

// ---------------------------------------------------------------------------
// Fused GEMM: C[M,512] = A[M,K] @ [Wl | Wr] + [bl | br]
// Wl, Wr are [K,256] each. Tile: 128x64x16, 256 threads, 8x4 per thread.
// ---------------------------------------------------------------------------
__global__ __launch_bounds__(256) void gemm_xlxr(
    const float* __restrict__ A, int M, int K,
    const float* __restrict__ Wl, const float* __restrict__ bl,
    const float* __restrict__ Wr, const float* __restrict__ br,
    float* __restrict__ C)
{
    constexpr int BM = 128, BN = 64, BK = 16;
    __shared__ float As[BK][BM];   // transposed A tile
    __shared__ float Bs[BK][BN];

    const int tid = threadIdx.x;
    const int m0 = blockIdx.x * BM;
    const int n0 = blockIdx.y * BN;

    const float* W; const float* bv; int nc0;
    if (n0 < 256) { W = Wl; bv = bl; nc0 = n0; }
    else          { W = Wr; bv = br; nc0 = n0 - 256; }

    const int ty = tid >> 4;         // 0..15  -> rows ty*8..ty*8+7
    const int tx = tid & 15;         // 0..15  -> cols tx*4..tx*4+3

    float acc[8][4];
    #pragma unroll
    for (int i = 0; i < 8; i++)
        #pragma unroll
        for (int j = 0; j < 4; j++) acc[i][j] = 0.f;

    const int ar0 = tid >> 2;            // 0..63
    const int akq = (tid & 3) * 4;       // 0,4,8,12
    const int bk  = tid >> 4;            // 0..15
    const int bnq = (tid & 15) * 4;      // 0..60

    const int nKt = K / BK;
    for (int kt = 0; kt < nKt; ++kt) {
        const int k0 = kt * BK;
        // A tile load (2 float4 per thread), store transposed
        #pragma unroll
        for (int h = 0; h < 2; ++h) {
            int row = ar0 + h * 64;
            int gm = m0 + row;
            float4 v = make_float4(0.f, 0.f, 0.f, 0.f);
            if (gm < M) v = *(const float4*)(A + (size_t)gm * K + k0 + akq);
            As[akq + 0][row] = v.x;
            As[akq + 1][row] = v.y;
            As[akq + 2][row] = v.z;
            As[akq + 3][row] = v.w;
        }
        // B tile load (1 float4 per thread)
        {
            float4 v = *(const float4*)(W + (size_t)(k0 + bk) * 256 + nc0 + bnq);
            *(float4*)&Bs[bk][bnq] = v;
        }
        __syncthreads();
        #pragma unroll
        for (int kk = 0; kk < BK; ++kk) {
            float a[8], b[4];
            *(float4*)&a[0] = *(const float4*)&As[kk][ty * 8];
            *(float4*)&a[4] = *(const float4*)&As[kk][ty * 8 + 4];
            *(float4*)&b[0] = *(const float4*)&Bs[kk][tx * 4];
            #pragma unroll
            for (int i = 0; i < 8; i++)
                #pragma unroll
                for (int j = 0; j < 4; j++)
                    acc[i][j] = fmaf(a[i], b[j], acc[i][j]);
        }
        __syncthreads();
    }

    float bvals[4];
    #pragma unroll
    for (int j = 0; j < 4; j++) bvals[j] = bv[nc0 + tx * 4 + j];
    #pragma unroll
    for (int i = 0; i < 8; i++) {
        int gm = m0 + ty * 8 + i;
        if (gm < M) {
            float4 o;
            o.x = acc[i][0] + bvals[0];
            o.y = acc[i][1] + bvals[1];
            o.z = acc[i][2] + bvals[2];
            o.w = acc[i][3] + bvals[3];
            *(float4*)(C + (size_t)gm * 512 + n0 + tx * 4) = o;
        }
    }
}

// ---------------------------------------------------------------------------
// Fused per-node GATv2 kernel: one block = one dst node, 256 threads = 256
// channels, wave w = head w. Online softmax over incoming edges; ea computed
// on the fly with We held in registers.
// ---------------------------------------------------------------------------
__global__ __launch_bounds__(256) void gat_node_kernel(
    const float* __restrict__ xlxr,       // [N,512]: cols 0..255 = xl, 256..511 = xr
    const float* __restrict__ edge_attr,  // [E,32]
    const float* __restrict__ We,         // [32,256]
    const float* __restrict__ att,        // [4,64] flat = [256]
    const float* __restrict__ bias,       // [256]
    const int* __restrict__ row_ptr,      // [N+1]
    const int2* __restrict__ col,         // [E] (src, eid)
    float* __restrict__ hout)             // [N,256]
{
    const int n = blockIdx.x;
    const int c = threadIdx.x;            // 0..255; head = c>>6

    const float att_c  = att[c];
    const float bias_c = bias[c];

    float we_reg[32];
    #pragma unroll
    for (int k = 0; k < 32; ++k) we_reg[k] = We[k * 256 + c];

    const float xr_c = xlxr[(size_t)n * 512 + 256 + c];

    float m_run = -3.0e38f;
    float s_run = 0.f;
    float accum = 0.f;

    const int e0 = row_ptr[n];
    const int e1 = row_ptr[n + 1];

    for (int j = e0; j < e1; ++j) {
        int2 se = col[j];
        const int srcn = se.x;
        const int eid  = se.y;

        float xl_c = xlxr[(size_t)srcn * 512 + c];

        const float4* ep = (const float4*)(edge_attr + (size_t)eid * 32);
        float ea = 0.f;
        #pragma unroll
        for (int q = 0; q < 8; ++q) {
            float4 v = ep[q];
            ea = fmaf(v.x, we_reg[4 * q + 0], ea);
            ea = fmaf(v.y, we_reg[4 * q + 1], ea);
            ea = fmaf(v.z, we_reg[4 * q + 2], ea);
            ea = fmaf(v.w, we_reg[4 * q + 3], ea);
        }

        float msg = xl_c + xr_c + ea;
        msg = (msg > 0.f) ? msg : NEG_SLOPE * msg;
        float part = msg * att_c;

        // wave (=head) reduction over 64 channels -> logit, uniform in wave
        #pragma unroll
        for (int off = 32; off > 0; off >>= 1)
            part += __shfl_xor(part, off, 64);
        const float logit = part;

        const float new_m = fmaxf(m_run, logit);
        const float p  = __expf(logit - new_m);
        const float sc = __expf(m_run - new_m);
        s_run = s_run * sc + p;
        accum = accum * sc + p * xl_c;
        m_run = new_m;
    }

    float outv = (e1 > e0) ? (accum / s_run) : 0.f;
    outv += bias_c;
    hout[(size_t)n * 256 + c] = fmaxf(outv, 0.f);   // fused ReLU
}

// ---------------------------------------------------------------------------
// Final projection: out[n] = h[n,:] @ W_out + b_out. One wave per node.
// ---------------------------------------------------------------------------
__global__ __launch_bounds__(256) void final_out_kernel(
    const float* __restrict__ h, const float* __restrict__ Wout,
    const float* __restrict__ bout, float* __restrict__ out, int N)
{
    const int wid  = threadIdx.x >> 6;
    const int lane = threadIdx.x & 63;
    const int n = blockIdx.x * 4 + wid;
    if (n >= N) return;
    float s = 0.f;
    #pragma unroll
    for (int q = 0; q < 4; ++q) {
        int cidx = lane + q * 64;
        s = fmaf(h[(size_t)n * 256 + cidx], Wout[cidx], s);
    }
    #pragma unroll
    for (int off = 32; off > 0; off >>= 1)
        s += __shfl_xor(s, off, 64);
    if (lane == 0) out[n] = s + bout[0];
}

// ---------------------------------------------------------------------------
extern "C" void kernel_launch(void* const* d_in, const int* in_sizes, int n_in,
                              void* d_out, int out_size, void* d_ws, size_t ws_size,
                              hipStream_t stream) {
    const float* x         = (const float*)d_in[0];
    const int*   edge_idx  = (const int*)d_in[1];
    const float* edge_attr = (const float*)d_in[2];
    const float* W_l0 = (const float*)d_in[3];
    const float* b_l0 = (const float*)d_in[4];
    const float* W_r0 = (const float*)d_in[5];
    const float* b_r0 = (const float*)d_in[6];
    const float* W_e0 = (const float*)d_in[7];
    const float* att0 = (const float*)d_in[8];
    const float* bias0= (const float*)d_in[9];
    const float* W_l1 = (const float*)d_in[10];
    const float* b_l1 = (const float*)d_in[11];
    const float* W_r1 = (const float*)d_in[12];
    const float* b_r1 = (const float*)d_in[13];
    const float* W_e1 = (const float*)d_in[14];
    const float* att1 = (const float*)d_in[15];
    const float* bias1= (const float*)d_in[16];
    const float* W_out= (const float*)d_in[17];
    const float* b_out= (const float*)d_in[18];

    const int N = in_sizes[0] / 512;      // 50000
    const int E = in_sizes[1] / 2;        // 800000

    const int* src = edge_idx;
    const int* dst = edge_idx + E;

    // workspace layout (all offsets 64B-aligned)
    char* ws = (char*)d_ws;
    float* bufA   = (float*)(ws);                                   // [N,512]
    size_t offB   = (size_t)N * 512 * 4;                            // 102.4 MB
    float* bufB   = (float*)(ws + offB);                            // [N,256]
    size_t offRP  = offB + (size_t)N * 256 * 4;                     // 153.6 MB
    int*   row_ptr= (int*)(ws + offRP);                             // [N+1]
    size_t offCur = offRP + (((size_t)(N + 1) * 4 + 63) & ~(size_t)63);
    int*   cursor = (int*)(ws + offCur);                            // [N] (also hist cnt)
    size_t offCol = offCur + (((size_t)N * 4 + 63) & ~(size_t)63);
    int2*  col    = (int2*)(ws + offCol);                           // [E]

    // ---- CSR build (dst shared by both layers) ----
    hipMemsetAsync(cursor, 0, (size_t)N * 4, stream);
    hist_kernel<<<(E + 255) / 256, 256, 0, stream>>>(dst, cursor, E);
    scan_kernel<<<1, 1024, 0, stream>>>(cursor, row_ptr, N, E);
    copy_int_kernel<<<(N + 255) / 256, 256, 0, stream>>>(row_ptr, cursor, N);
    scatter_kernel<<<(E + 255) / 256, 256, 0, stream>>>(src, dst, cursor, col, E);

    // ---- Layer 0 ----
    {
        dim3 grid((N + 127) / 128, 8);
        gemm_xlxr<<<grid, 256, 0, stream>>>(x, N, 512, W_l0, b_l0, W_r0, b_r0, bufA);
        gat_node_kernel<<<N, 256, 0, stream>>>(bufA, edge_attr, W_e0, att0, bias0,
                                               row_ptr, col, bufB);
    }
    // ---- Layer 1 ----
    {
        dim3 grid((N + 127) / 128, 8);
        gemm_xlxr<<<grid, 256, 0, stream>>>(bufB, N, 256, W_l1, b_l1, W_r1, b_r1, bufA);
        gat_node_kernel<<<N, 256, 0, stream>>>(bufA, edge_attr, W_e1, att1, bias1,
                                               row_ptr, col, bufB);
    }
    // ---- Output projection ----
    final_out_kernel<<<(N + 3) / 4, 256, 0, stream>>>(bufB, W_out, b_out, (float*)d_out, N);
}